// Round 1
// 149.061 us; speedup vs baseline: 1.0879x; 1.0879x over previous
//
#include <hip/hip_runtime.h>
#include <stdint.h>

typedef unsigned short u16;
typedef short s16x8 __attribute__((ext_vector_type(8)));
typedef float f32x4 __attribute__((ext_vector_type(4)));

#define SQ 2048
#define DH 64
#define BM 64
#define BN 64
#define STR 72             // prep-only LDS transpose stride (shorts)
#define SPECIAL_START 2040
#define NBH 32             // b*h
#define NKV 8              // b*hk
#define NQT 32
#define NITEMS (NBH * NQT) // 1024 work items (bh, qt)
#define ATTN_GRID 896      // < NITEMS so the queue can rebalance
// softclamp+softmax folded to exp2: p = 2^( t*poly(t*t) - KEF ), t = s * K1F
#define K1F  0.18033688011112043f    // 0.125 * log2(e)
#define KPAF 4.9244826e-9f           // (2/15)*k^2, k = (0.02/log2e)^2
#define KPBF -6.406040185576019e-5f  // -k/3
#define KEF  36.067376022224085f     // 25 * log2(e)  (constant softmax shift = 25)

union U8 { s16x8 v; short e[8]; };
union F4 { f32x4 v; float e[4]; };

__device__ __forceinline__ u16 f2bf(float x) {  // round-to-nearest-even (fallback path)
    uint32_t u = __float_as_uint(x);
    return (u16)((u + 0x7fffu + ((u >> 16) & 1u)) >> 16);
}
__device__ __forceinline__ uint32_t pkbf(float a, float b) {  // pack 2 bf16, 1 instr
    uint32_t r;
    asm("v_cvt_pk_bf16_f32 %0, %1, %2" : "=v"(r) : "v"(a), "v"(b));
    return r;
}
__device__ __forceinline__ float exp2hw(float x) {
    float r; asm("v_exp_f32 %0, %1" : "=v"(r) : "v"(x)); return r;
}
__device__ __forceinline__ float2 fsincos(float ang) {  // {sin, cos}, fast HW path
    float r = ang * 0.15915494309189535f;   // radians -> revolutions
    r -= floorf(r);
    float s, c;
    asm("v_sin_f32 %0, %1" : "=v"(s) : "v"(r));
    asm("v_cos_f32 %0, %1" : "=v"(c) : "v"(r));
    return make_float2(s, c);
}

// ---- prep: V tiles (plain transpose; swizzle applied at LDS staging in attn),
//      Q/K rope rows with HW sincos; also resets the work-queue counter ----
#define VTILES (NKV * 32)                 // 256 tile-blocks
#define RQ (NBH * SQ)
#define RK (NKV * SQ)
#define QKBLK ((RQ + RK) / 32)            // 2560 row-blocks (32 rows each)
__global__ __launch_bounds__(256)
void prep_kernel(const float* __restrict__ qg, const float* __restrict__ kg,
                 const float* __restrict__ vg, const float* __restrict__ rotg,
                 u16* __restrict__ qp, u16* __restrict__ kp, u16* __restrict__ vp,
                 uint32_t* __restrict__ cnt, int init_cnt)
{
    const int tid = threadIdx.x;
    if (init_cnt && blockIdx.x == 0 && tid == 0) *cnt = 0u;
    if (blockIdx.x < VTILES) {
        // --- V: one 64x64 tile, transpose through LDS; vp[tile][d][kv] = V[kv][d] ---
        __shared__ short Vls[64 * STR];
        const int tile = blockIdx.x;                   // bkv*32 + kt
        const float* src = vg + ((size_t)(tile >> 5) * SQ + (size_t)(tile & 31) * 64) * DH;
        {
            int kv = tid >> 2, c0 = (tid & 3) * 16;
            const float* s4 = src + (size_t)kv * DH + c0;
            float4 f0 = *(const float4*)(s4);
            float4 f1 = *(const float4*)(s4 + 4);
            float4 f2 = *(const float4*)(s4 + 8);
            float4 f3 = *(const float4*)(s4 + 12);
            uint4 w0 = make_uint4(pkbf(f0.x, f0.y), pkbf(f0.z, f0.w),
                                  pkbf(f1.x, f1.y), pkbf(f1.z, f1.w));
            uint4 w1 = make_uint4(pkbf(f2.x, f2.y), pkbf(f2.z, f2.w),
                                  pkbf(f3.x, f3.y), pkbf(f3.z, f3.w));
            *(uint4*)&Vls[kv * STR + c0]     = w0;
            *(uint4*)&Vls[kv * STR + c0 + 8] = w1;
        }
        __syncthreads();
        {
            int d = tid >> 2, c0 = (tid & 3) * 16;
            U8 o0, o1;
#pragma unroll
            for (int j = 0; j < 16; j++)
                (j < 8 ? o0 : o1).e[j & 7] = Vls[(c0 + j) * STR + d];  // plain transpose
            u16* dst = vp + (((size_t)tile * 64 + d) << 6) + c0;
            *(s16x8*)dst       = o0.v;
            *(s16x8*)(dst + 8) = o1.v;
        }
    } else {
        // --- Q/K rope: 32 rows per block, 8 elems per thread; HW sin/cos ---
        int bx = blockIdx.x - VTILES;
        int r8 = tid >> 3, c0 = (tid & 7) * 4;      // c0 in 0..28 (<32)
        int R = bx * 32 + r8;
        const int isQ = (R < RQ);
        const int r = isQ ? R : R - RQ;
        const int s = r & (SQ - 1);
        const float* src = (isQ ? qg : kg) + (size_t)r * DH;
        u16*         dst = (isQ ? qp : kp) + (size_t)r * DH;
        float4 a  = *(const float4*)(src + c0);
        float4 b  = *(const float4*)(src + c0 + 32);
        float4 rv = *(const float4*)(rotg + (size_t)s * DH + c0);
        float2 s0 = fsincos(rv.x), s1 = fsincos(rv.y),
               s2 = fsincos(rv.z), s3 = fsincos(rv.w);
        float lo0 = a.x * s0.y - b.x * s0.x, hi0 = b.x * s0.y + a.x * s0.x;
        float lo1 = a.y * s1.y - b.y * s1.x, hi1 = b.y * s1.y + a.y * s1.x;
        float lo2 = a.z * s2.y - b.z * s2.x, hi2 = b.z * s2.y + a.z * s2.x;
        float lo3 = a.w * s3.y - b.w * s3.x, hi3 = b.w * s3.y + a.w * s3.x;
        *(uint2*)(dst + c0)      = make_uint2(pkbf(lo0, lo1), pkbf(lo2, lo3));
        *(uint2*)(dst + c0 + 32) = make_uint2(pkbf(hi0, hi1), pkbf(hi2, hi3));
    }
}

// S^T = K.Q^T via mfma(A=K,B=Q)   -> C: col(l15)=q, row(quad*4+c)=kv
// O^T = V^T.P via mfma(A=Vt,B=P)  -> C: col(l15)=q, row(quad*4+c)=d
// LDS layout: stride 64 shorts/row, XOR swizzle: short_idx ^= ((row&7)<<3)
// mode: 0 = inline rope fallback, 1 = pre-staged static grid, 2 = pre-staged + work queue
__global__ __launch_bounds__(256, 4)
void attn_kernel(const float* __restrict__ qg, const float* __restrict__ kg,
                 const float* __restrict__ vg, const float* __restrict__ rotg,
                 int mode,
                 const u16* __restrict__ qp, const u16* __restrict__ kp,
                 const u16* __restrict__ vp, uint32_t* __restrict__ cnt,
                 float* __restrict__ outg)
{
    const int tid = threadIdx.x;
    const int wv = tid >> 6, lane = tid & 63;
    const int l15 = lane & 15, quad = lane >> 4;
    const int r4 = tid >> 2, c16 = (tid & 3) * 16;
    const int swl = (l15 & 7) << 3;   // fragment-row swizzle (shorts); rows mb*16+l15 share it
    const int swr = (r4 & 7) << 3;    // staging-row swizzle

    __shared__ __align__(16) short QPs[BM * 64];     // Q tile, then P rows (wave-private)
    __shared__ __align__(16) short Ks[2][BN * 64];   // double-buffered K
    __shared__ __align__(16) short Vt[2][DH * 64];   // double-buffered V^T
    // queue broadcast slot aliased into Ks[1] tail: previous item's last read of Ks[1]
    // is before the pop barrier; Ks[1] is fully restaged (kt=1) before its next read.
    volatile int* s_w = (volatile int*)&Ks[1][BN * 64 - 2];

    int done = 0;
    for (;;) {
        int qt, bh;
        if (mode == 2) {
            __syncthreads();                       // prev item's LDS reads done
            if (tid == 0) *s_w = (int)atomicAdd(cnt, 1u);
            __syncthreads();
            const int w = *s_w;
            if (w >= NITEMS) break;
            qt = (NQT - 1) - (w >> 5);             // heavy-first (nkt descending)
            bh = w & (NBH - 1);
        } else {
            if (done) break;
            done = 1;
            const int x = blockIdx.x;
            qt = (x & 1) ? (31 - (x >> 1)) : (x >> 1);
            bh = blockIdx.y;
        }

        const int bb = bh >> 4, hh = bh & 15;
        const int bkv = bb * 4 + (hh >> 2);
        const int qs = qt * BM;
        const size_t qbase  = ((size_t)bh * SQ + qs) * DH;
        const size_t kvbase = ((size_t)bkv * SQ) * DH;
        const int nkt = (qt / 4 + 1) * 4;          // block-causal: tiles fully allowed
        const int qglob = qs + wv * 16 + l15;

        // ---- K/V register prefetch ----
        s16x8 kpr0, kpr1, vpr0, vpr1;
        auto pref = [&](int kt) {
            const u16* srck = kp + kvbase + (size_t)(kt * BN + r4) * DH + c16;
            kpr0 = *(const s16x8*)srck;
            kpr1 = *(const s16x8*)(srck + 8);
            const u16* srcv = vp + (((size_t)(bkv * 32 + kt) * 64 + r4) << 6) + c16;
            vpr0 = *(const s16x8*)srcv;
            vpr1 = *(const s16x8*)(srcv + 8);
        };
        if (mode) pref(0);

        // ---- stage Q tile (swizzled) ----
        if (mode) {
            const u16* src = qp + qbase + (size_t)r4 * DH + c16;
            *(s16x8*)&QPs[r4 * 64 + (c16 ^ swr)]       = *(const s16x8*)src;
            *(s16x8*)&QPs[r4 * 64 + ((c16 + 8) ^ swr)] = *(const s16x8*)(src + 8);
        } else {
            int rr = tid >> 2, c0 = (tid & 3) * 8;
            int srow = qs + rr;
            const float* gq = qg + qbase + (size_t)rr * DH;
            float a[8], b[8];
            *(float4*)&a[0] = *(const float4*)(gq + c0);
            *(float4*)&a[4] = *(const float4*)(gq + c0 + 4);
            *(float4*)&b[0] = *(const float4*)(gq + c0 + 32);
            *(float4*)&b[4] = *(const float4*)(gq + c0 + 36);
            U8 o0, o1;
#pragma unroll
            for (int j = 0; j < 8; j++) {
                float cs, sn;
                sincosf(rotg[(size_t)srow * DH + ((c0 + j) & 31)], &sn, &cs);
                o0.e[j] = (short)f2bf(a[j] * cs - b[j] * sn);
                o1.e[j] = (short)f2bf(b[j] * cs + a[j] * sn);
            }
            int sw2 = (rr & 7) << 3;
            *(s16x8*)&QPs[rr * 64 + (c0 ^ sw2)]        = o0.v;
            *(s16x8*)&QPs[rr * 64 + ((c0 + 32) ^ sw2)] = o1.v;
        }
        __syncthreads();

        // ---- preload Q fragments: B[n=q(l15)][k=quad*8+j] ----
        s16x8 qf[2];
#pragma unroll
        for (int ks = 0; ks < 2; ks++)
            qf[ks] = *(const s16x8*)&QPs[(wv * 16 + l15) * 64 + ((ks * 32 + quad * 8) ^ swl)];

        F4 oa[4];
#pragma unroll
        for (int mb = 0; mb < 4; mb++) oa[mb].v = (f32x4){0.f, 0.f, 0.f, 0.f};
        float lsum = 0.f;

#pragma unroll 2
        for (int kt = 0; kt < nkt; kt++) {
            const int cb = kt & 1;
            // stage tile kt into buf[cb] (other buffer is being read at most) — no pre-barrier
            if (mode) {
                *(s16x8*)&Ks[cb][r4 * 64 + (c16 ^ swr)]       = kpr0;
                *(s16x8*)&Ks[cb][r4 * 64 + ((c16 + 8) ^ swr)] = kpr1;
                *(s16x8*)&Vt[cb][r4 * 64 + (c16 ^ swr)]       = vpr0;
                *(s16x8*)&Vt[cb][r4 * 64 + ((c16 + 8) ^ swr)] = vpr1;
                if (kt + 1 < nkt) pref(kt + 1);   // latency hides under compute below
            } else {
                {   // K rope inline (fallback)
                    int rr = tid >> 2, c0 = (tid & 3) * 8;
                    int srow = kt * BN + rr;
                    const float* gk = kg + kvbase + (size_t)srow * DH;
                    float a[8], b[8];
                    *(float4*)&a[0] = *(const float4*)(gk + c0);
                    *(float4*)&a[4] = *(const float4*)(gk + c0 + 4);
                    *(float4*)&b[0] = *(const float4*)(gk + c0 + 32);
                    *(float4*)&b[4] = *(const float4*)(gk + c0 + 36);
                    U8 o0, o1;
#pragma unroll
                    for (int j = 0; j < 8; j++) {
                        float cs, sn;
                        sincosf(rotg[(size_t)srow * DH + ((c0 + j) & 31)], &sn, &cs);
                        o0.e[j] = (short)f2bf(a[j] * cs - b[j] * sn);
                        o1.e[j] = (short)f2bf(b[j] * cs + a[j] * sn);
                    }
                    int sw2 = (rr & 7) << 3;
                    *(s16x8*)&Ks[cb][rr * 64 + (c0 ^ sw2)]        = o0.v;
                    *(s16x8*)&Ks[cb][rr * 64 + ((c0 + 32) ^ sw2)] = o1.v;
                }
                {   // V transpose inline (fallback)
                    int rr = tid >> 2, c0 = (tid & 3) * 16;
                    const float* gv = vg + kvbase + (size_t)(kt * BN + rr) * DH;
                    float vv[16];
#pragma unroll
                    for (int t = 0; t < 4; t++)
                        *(float4*)&vv[t * 4] = *(const float4*)(gv + c0 + t * 4);
#pragma unroll
                    for (int j = 0; j < 16; j++) {
                        int d = c0 + j;
                        Vt[cb][d * 64 + (rr ^ ((d & 7) << 3))] = (short)f2bf(vv[j]);
                    }
                }
            }
            __syncthreads();   // buf[cb] staged; prev buffer free for next iter's writes

            // ---- QK^T: S^T[kv][q] ----
            F4 sa[4];
#pragma unroll
            for (int mb = 0; mb < 4; mb++) sa[mb].v = (f32x4){0.f, 0.f, 0.f, 0.f};
            __builtin_amdgcn_s_setprio(1);
#pragma unroll
            for (int ks = 0; ks < 2; ks++) {
#pragma unroll
                for (int mb = 0; mb < 4; mb++) {
                    s16x8 kf = *(const s16x8*)&Ks[cb][(mb * 16 + l15) * 64 + ((ks * 32 + quad * 8) ^ swl)];
                    sa[mb].v = __builtin_amdgcn_mfma_f32_16x16x32_bf16(kf, qf[ks], sa[mb].v, 0, 0, 0);
                }
            }
            __builtin_amdgcn_s_setprio(0);

            // ---- softclamp + constant-shift softmax, folded to exp2 (5 VALU + 1 trans/elem) ----
            F4 pa[4];
#pragma unroll
            for (int mb = 0; mb < 4; mb++)
#pragma unroll
                for (int c = 0; c < 4; c++) {
                    float t  = sa[mb].e[c] * K1F;
                    float w2 = t * t;
                    float poly = fmaf(w2, fmaf(w2, KPAF, KPBF), 1.0f);
                    pa[mb].e[c] = exp2hw(fmaf(t, poly, -KEF));
                }
            if (kt == 31 && qglob < SPECIAL_START) {
#pragma unroll
                for (int mb = 0; mb < 4; mb++)
#pragma unroll
                    for (int c = 0; c < 4; c++) {
                        int kvglob = kt * BN + mb * 16 + quad * 4 + c;
                        if (kvglob >= SPECIAL_START) pa[mb].e[c] = 0.f;
                    }
            }
            short* prow = &QPs[(wv * 16 + l15) * 64];
#pragma unroll
            for (int mb = 0; mb < 4; mb++) {
                lsum += pa[mb].e[0] + pa[mb].e[1] + pa[mb].e[2] + pa[mb].e[3];
                uint2 pw = make_uint2(pkbf(pa[mb].e[0], pa[mb].e[1]),
                                      pkbf(pa[mb].e[2], pa[mb].e[3]));
                *(uint2*)&prow[(mb * 16 + quad * 4) ^ swl] = pw;  // 8B-aligned b64 store
            }

            // ---- PV: O^T[d][q] += Vt.P (P round-trip wave-private: no barrier) ----
            __builtin_amdgcn_s_setprio(1);
#pragma unroll
            for (int ks = 0; ks < 2; ks++) {
                s16x8 pf = *(const s16x8*)&prow[(ks * 32 + quad * 8) ^ swl];
#pragma unroll
                for (int mb = 0; mb < 4; mb++) {
                    s16x8 vf = *(const s16x8*)&Vt[cb][(mb * 16 + l15) * 64 + ((ks * 32 + quad * 8) ^ swl)];
                    oa[mb].v = __builtin_amdgcn_mfma_f32_16x16x32_bf16(vf, pf, oa[mb].v, 0, 0, 0);
                }
            }
            __builtin_amdgcn_s_setprio(0);
        }

        // ---- final lsum reduction across quads (kv partitioned by quad) ----
        lsum += __shfl_xor(lsum, 16, 64);
        lsum += __shfl_xor(lsum, 32, 64);

        // ---- epilogue ----
        float rl = 1.0f / lsum;
        int qrow = qs + wv * 16 + l15;
        float* orow = outg + ((size_t)bh * SQ + qrow) * DH;
#pragma unroll
        for (int mb = 0; mb < 4; mb++) {
            int d0 = mb * 16 + quad * 4;
            *(float4*)(orow + d0) = make_float4(oa[mb].e[0] * rl, oa[mb].e[1] * rl,
                                                oa[mb].e[2] * rl, oa[mb].e[3] * rl);
        }
    }
}

extern "C" void kernel_launch(void* const* d_in, const int* in_sizes, int n_in,
                              void* d_out, int out_size, void* d_ws, size_t ws_size,
                              hipStream_t stream) {
    const float* q   = (const float*)d_in[0];
    const float* k   = (const float*)d_in[1];
    const float* v   = (const float*)d_in[2];
    const float* rot = (const float*)d_in[3];
    float* out = (float*)d_out;

    char* w = (char*)d_ws;
    const size_t q_bytes = (size_t)NBH * SQ * DH * sizeof(u16);     // 8 MiB
    const size_t k_bytes = (size_t)NKV * SQ * DH * sizeof(u16);     // 2 MiB
    const size_t v_bytes = k_bytes;                                 // 2 MiB
    const size_t base = q_bytes + k_bytes + v_bytes;
    u16* qp = (u16*)w;
    u16* kp = (u16*)(w + q_bytes);
    u16* vp = (u16*)(w + q_bytes + k_bytes);
    uint32_t* cnt = (uint32_t*)(w + base);

    int mode = 0;
    if (ws_size >= base + sizeof(uint32_t)) mode = 2;   // queue counter fits
    else if (ws_size >= base) mode = 1;                 // pre-staged, static grid

    if (mode)
        hipLaunchKernelGGL(prep_kernel, dim3(VTILES + QKBLK), dim3(256), 0, stream,
                           q, k, v, rot, qp, kp, vp, cnt, (mode == 2) ? 1 : 0);

    if (mode == 2)
        hipLaunchKernelGGL(attn_kernel, dim3(ATTN_GRID), dim3(256), 0, stream,
                           q, k, v, rot, mode, qp, kp, vp, cnt, out);
    else
        hipLaunchKernelGGL(attn_kernel, dim3(32, NBH), dim3(256), 0, stream,
                           q, k, v, rot, mode, qp, kp, vp, cnt, out);
}